// Round 11
// baseline (885.059 us; speedup 1.0000x reference)
//
#include <hip/hip_runtime.h>

#define HIDDEN 450
#define MAX_NB 15
#define N_ATOMS 20000
#define N_BONDS 40000
#define N_MESS  16000
#define N_MOLS  1000
#define KPAD    512     // padded concat-K: [feat 0..39 | nei 40..489 | pad]
#define MSTRIDE 456     // message/base row stride = 912B = 57 x 16B chunks
#define FSTRIDE 64      // packed feature row stride (chunks 0..7)
#define BM      80      // fused-kernel M-tile: 40000/80 = 500 tiles <= 512 slots
                        // -> SINGLE ROUND; 80KB LDS x 2 blocks = 160KB/CU exact

typedef unsigned int uint;
typedef unsigned short ushort;
typedef __bf16 bf16x8 __attribute__((ext_vector_type(8)));
typedef float  f32x4  __attribute__((ext_vector_type(4)));

__device__ __forceinline__ ushort f2bf(float f) {
    uint u = __builtin_bit_cast(uint, f);
    u += 0x7fffu + ((u >> 16) & 1u);     // RNE
    return (ushort)(u >> 16);
}
__device__ __forceinline__ float bfhi(uint w) {
    return __builtin_bit_cast(float, w & 0xffff0000u);
}
__device__ __forceinline__ float bflo(uint w) {
    return __builtin_bit_cast(float, w << 16);
}

// ---------------- pack kernels (run once per launch) ----------------

__global__ __launch_bounds__(256) void pack_tree(const float* __restrict__ tree,
                                                 ushort* __restrict__ tbuf) {
    const int r = blockIdx.x, t = threadIdx.x;
    if (t < 228) {
        uint p = 0;
        if (t < 225) {
            const float2 v = *(const float2*)&tree[(size_t)r * HIDDEN + 2 * t];
            p = (uint)f2bf(v.x) | ((uint)f2bf(v.y) << 16);
        }
        ((uint*)(tbuf + (size_t)r * MSTRIDE))[t] = p;
    }
}

__global__ __launch_bounds__(256) void pack_bonds(const float* __restrict__ fbonds,
                                                  ushort* __restrict__ Abuf) {
    const int r = blockIdx.x * 4 + (threadIdx.x >> 6);
    const int t = threadIdx.x & 63;
    if (r >= N_BONDS) return;
    Abuf[(size_t)r * FSTRIDE + t] = (t < 40) ? f2bf(fbonds[(size_t)r * 40 + t])
                                             : (ushort)0;
}

__global__ __launch_bounds__(256) void pack_atoms(const float* __restrict__ fatoms,
                                                  ushort* __restrict__ Aout) {
    const int r = blockIdx.x * 4 + (threadIdx.x >> 6);
    const int t = threadIdx.x & 63;
    if (r >= N_ATOMS) return;
    Aout[(size_t)r * FSTRIDE + t] = (t < 35) ? f2bf(fatoms[(size_t)r * 35 + t])
                                             : (ushort)0;
}

__global__ __launch_bounds__(256) void pack_w(const float* __restrict__ W_i,
                                              const float* __restrict__ W_h,
                                              const float* __restrict__ W_o,
                                              ushort* __restrict__ Wcat,
                                              ushort* __restrict__ Wocat) {
    const int n = blockIdx.x;  // 0..511
    for (int c = threadIdx.x; c < KPAD; c += 256) {
        float v = 0.0f, vo = 0.0f;
        if (n < HIDDEN) {
            if (c < 40)       v = W_i[(size_t)n * 40 + c];
            else if (c < 490) v = W_h[(size_t)n * HIDDEN + (c - 40)];
            if (c < 35)       vo = W_o[(size_t)n * 485 + c];
            else if (c >= 40 && c < 490) vo = W_o[(size_t)n * 485 + 35 + (c - 40)];
        }
        Wcat [(size_t)n * KPAD + c] = f2bf(v);
        Wocat[(size_t)n * KPAD + c] = f2bf(vo);
    }
}

// ---------------- static-base precompute: base[r] = sum_{idx<N_MESS} tbuf[idx] ----
// All 15 loads unconditional (invalid idx -> tbuf row 0 = zero padding slot);
// sched_barrier(0) after the batch keeps the batch in flight (MLP fence).
__global__ __launch_bounds__(256) void precompute_base(const int* __restrict__ g,
                                                       const ushort* __restrict__ tbuf,
                                                       ushort* __restrict__ base,
                                                       int nrows) {
    const int r_raw = blockIdx.x * 4 + (threadIdx.x >> 6);
    const int lane = threadIdx.x & 63;
    if (r_raw >= nrows) return;
    const int r = __builtin_amdgcn_readfirstlane(r_raw);   // wave-uniform -> SGPR
    const int* gr = g + (size_t)r * MAX_NB;
    const ushort* p[MAX_NB];
#pragma unroll
    for (int j = 0; j < MAX_NB; ++j) {
        const int idx = gr[j];
        p[j] = tbuf + (size_t)((idx < N_MESS) ? idx : 0) * MSTRIDE;
    }
    if (lane >= 57) return;
    const int off = lane * 8;
    uint4 w[MAX_NB];
#pragma unroll
    for (int j = 0; j < MAX_NB; ++j) w[j] = *(const uint4*)(p[j] + off);
    __builtin_amdgcn_sched_barrier(0);     // MLP fence: no sums above this line
    float acc[8] = {};
#pragma unroll
    for (int j = 0; j < MAX_NB; ++j) {
        acc[0] += bflo(w[j].x); acc[1] += bfhi(w[j].x);
        acc[2] += bflo(w[j].y); acc[3] += bfhi(w[j].y);
        acc[4] += bflo(w[j].z); acc[5] += bfhi(w[j].z);
        acc[6] += bflo(w[j].w); acc[7] += bfhi(w[j].w);
    }
    uint4 o;
    o.x = (uint)f2bf(acc[0]) | ((uint)f2bf(acc[1]) << 16);
    o.y = (uint)f2bf(acc[2]) | ((uint)f2bf(acc[3]) << 16);
    o.z = (uint)f2bf(acc[4]) | ((uint)f2bf(acc[5]) << 16);
    o.w = (uint)f2bf(acc[6]) | ((uint)f2bf(acc[7]) << 16);
    *(uint4*)(base + (size_t)r * MSTRIDE + off) = o;
}

// ---------------- first GEMM (K=64 on raw bond feats) ----------------
// C[M x 450] = relu(A[M x K] . W[450 x K]^T), K = KT*32, A stride AST ushorts.
template <int KT, int AST>
__global__ __launch_bounds__(256, 2) void mfma_gemm0(
    const ushort* __restrict__ A, int M,
    const ushort* __restrict__ W,
    ushort* __restrict__ gout, int mtiles) {
    __shared__ ushort At[64 * KT * 32];
    const int tid = threadIdx.x;
    const int id  = blockIdx.x;
    const int b     = id & 7;               // XCD residue
    const int n_blk = (id >> 3) & 1;
    const int m_blk = (id >> 4) * 8 + b;
    if (m_blk >= mtiles) return;            // uniform early-out (before barrier)
    const int m0 = m_blk * 64, n0 = n_blk * 256;
    const int CPR = KT * 4;                 // 16B chunks per LDS row

    {
        const int srow = tid >> 2;
        const int c0   = tid & 3;
        const ushort* gsrc = A + (size_t)min(m0 + srow, M - 1) * AST;
        ushort* lrow = At + srow * (KT * 32);
#pragma unroll
        for (int c = c0; c < CPR; c += 4) {
            const uint4 v = *(const uint4*)(gsrc + c * 8);
            *(uint4*)&lrow[(c ^ (srow & 7)) * 8] = v;
        }
    }
    __syncthreads();

    const int lane = tid & 63;
    const int wave = tid >> 6;
    const int wn = wave * 64;
    const int lr = lane & 15;
    const int lk = lane >> 4;

    size_t woff[4];
#pragma unroll
    for (int s = 0; s < 4; ++s)
        woff[s] = (size_t)(n0 + wn + s * 16 + lr) * KPAD + lk * 8;

    f32x4 acc[4][4];
#pragma unroll
    for (int i = 0; i < 4; ++i)
#pragma unroll
        for (int j = 0; j < 4; ++j) acc[i][j] = (f32x4){0.f, 0.f, 0.f, 0.f};

    bf16x8 wa[4], wb[4], afa[4];
#pragma unroll
    for (int s = 0; s < 4; ++s) wa[s] = *(const bf16x8*)&W[woff[s]];
#pragma unroll
    for (int s = 0; s < 4; ++s)
        wb[s] = (KT > 1) ? *(const bf16x8*)&W[woff[s] + 32] : wa[s];
#pragma unroll
    for (int mt = 0; mt < 4; ++mt) {
        const int row = mt * 16 + lr;
        afa[mt] = *(const bf16x8*)&At[(row * CPR + (lk ^ (row & 7))) * 8];
    }

#pragma unroll
    for (int i = 0; i < KT; ++i) {
        bf16x8 wc[4], afb[4];
        if (i + 2 < KT) {
#pragma unroll
            for (int s = 0; s < 4; ++s)
                wc[s] = *(const bf16x8*)&W[woff[s] + (size_t)(i + 2) * 32];
        }
        if (i + 1 < KT) {
#pragma unroll
            for (int mt = 0; mt < 4; ++mt) {
                const int row = mt * 16 + lr;
                const int chunk = (((i + 1) * 4 + lk)) ^ (row & 7);
                afb[mt] = *(const bf16x8*)&At[(row * CPR + chunk) * 8];
            }
        }
#pragma unroll
        for (int mt = 0; mt < 4; ++mt)
#pragma unroll
            for (int nt = 0; nt < 4; ++nt)
                acc[mt][nt] = __builtin_amdgcn_mfma_f32_16x16x32_bf16(
                    afa[mt], wa[nt], acc[mt][nt], 0, 0, 0);
        if (i + 1 < KT) {
#pragma unroll
            for (int s = 0; s < 4; ++s) wa[s] = wb[s];
#pragma unroll
            for (int mt = 0; mt < 4; ++mt) afa[mt] = afb[mt];
        }
        if (i + 2 < KT) {
#pragma unroll
            for (int s = 0; s < 4; ++s) wb[s] = wc[s];
        }
    }

    const int col_l = lane & 15;
    const int rbase = (lane >> 4) * 4;
#pragma unroll
    for (int mt = 0; mt < 4; ++mt) {
        const int mbase = m0 + mt * 16 + rbase;
#pragma unroll
        for (int nt = 0; nt < 4; ++nt) {
            const int n = n0 + wn + nt * 16 + col_l;
#pragma unroll
            for (int reg = 0; reg < 4; ++reg) {
                const int m = mbase + reg;
                if (m >= M) continue;
                if (n < HIDDEN)
                    gout[(size_t)m * MSTRIDE + n] = f2bf(fmaxf(acc[mt][nt][reg], 0.0f));
                else if (n < MSTRIDE)
                    gout[(size_t)m * MSTRIDE + n] = 0;   // keep pad cols zero
            }
        }
    }
}

// ---------------- fused gather + GEMM (BM=80, single-round grid) ----------
// Per block: 80 rows x full N=512. 8 waves / 512 threads; LDS 80KB ->
// 2 blocks/CU = 160KB (full pool). Bonds: 500 tiles, atoms: 250 tiles -
// both <= 512 resident slots -> ONE dispatch round, uniform 1 tile/block
// (the only structure proven traffic-clean across R4-R10; all multi-tile
// and dynamic-queue variants amplified HBM traffic). This removes R4's
// round-2 tail (625 tiles on 512 slots = 39% wasted slots = the 0.61
// utilization that capped gather rate at 2.2 of 3.6 TB/s).
// Stage: each wave gather-sums 10 rows straight into the swizzled LDS
// A-tile; base + 15 unconditional neighbor loads back-to-back (invalid ->
// 912B zero row), sched_barrier MLP fence, sums. Wave-uniform row scalars.
// Compute: TWO passes to keep peak regs at R4's proven 128 (64 arch + 64
// acc): pass A rows 0..63 (acc[4][4], R4's exact K-loop), pass B rows
// 64..79 (acc[4], W re-read from L2 - negligible). KT=16, W 2-deep, A 1-deep.
// MODE 0: bf16 store to gout. MODE 1: bias+relu+molecule atomicAdd (run-merge).
template <int MODE>
__global__ __launch_bounds__(512, 4) void fused_gg(
    const int* __restrict__ g,
    const ushort* __restrict__ base,
    const ushort* __restrict__ gin,
    const ushort* __restrict__ zrow,
    const ushort* __restrict__ feat,
    const ushort* __restrict__ W,
    const float* __restrict__ bias, const int* __restrict__ mol_ids,
    ushort* __restrict__ gout, float* __restrict__ aout, int M) {
    __shared__ ushort At[BM * KPAD];        // 80 rows x 64 chunks, 80KB
    const int tid  = threadIdx.x;
    const int lane = tid & 63;
    const int wave = tid >> 6;
    const int m0 = blockIdx.x * BM;

    // ---- stage: gather-sum directly into swizzled LDS (10 rows per wave) ---
#pragma unroll 1
    for (int rr = 0; rr < 10; ++rr) {
        const int r = wave * 10 + rr;
        const int m = __builtin_amdgcn_readfirstlane(min(m0 + r, M - 1));
        const int sw = r & 7;
        ushort* lrow = At + r * KPAD;
        const int* gr = g + (size_t)m * MAX_NB;
        const ushort* p[MAX_NB];
#pragma unroll
        for (int j = 0; j < MAX_NB; ++j) {
            const int row = gr[j] - N_MESS;
            p[j] = (row >= 0) ? gin + (size_t)row * MSTRIDE : zrow;
        }
        if (lane < 57) {
            const int off = lane * 8;
            const uint4 b = *(const uint4*)(base + (size_t)m * MSTRIDE + off);
            uint4 w[MAX_NB];
#pragma unroll
            for (int j = 0; j < MAX_NB; ++j) w[j] = *(const uint4*)(p[j] + off);
            __builtin_amdgcn_sched_barrier(0);  // MLP fence: 16 loads in flight
            float acc[8];
            acc[0] = bflo(b.x); acc[1] = bfhi(b.x);
            acc[2] = bflo(b.y); acc[3] = bfhi(b.y);
            acc[4] = bflo(b.z); acc[5] = bfhi(b.z);
            acc[6] = bflo(b.w); acc[7] = bfhi(b.w);
#pragma unroll
            for (int j = 0; j < MAX_NB; ++j) {
                acc[0] += bflo(w[j].x); acc[1] += bfhi(w[j].x);
                acc[2] += bflo(w[j].y); acc[3] += bfhi(w[j].y);
                acc[4] += bflo(w[j].z); acc[5] += bfhi(w[j].z);
                acc[6] += bflo(w[j].w); acc[7] += bfhi(w[j].w);
            }
            uint4 o;
            o.x = (uint)f2bf(acc[0]) | ((uint)f2bf(acc[1]) << 16);
            o.y = (uint)f2bf(acc[2]) | ((uint)f2bf(acc[3]) << 16);
            o.z = (uint)f2bf(acc[4]) | ((uint)f2bf(acc[5]) << 16);
            o.w = (uint)f2bf(acc[6]) | ((uint)f2bf(acc[7]) << 16);
            *(uint4*)&lrow[((5 + lane) ^ sw) * 8] = o;   // nei chunks 5..61
        } else {
            const int c = (lane < 62) ? (lane - 57) : lane;  // feat 0..4 | pad 62,63
            uint4 v = (uint4){0u, 0u, 0u, 0u};
            if (lane < 62)
                v = *(const uint4*)(feat + (size_t)m * FSTRIDE + (lane - 57) * 8);
            *(uint4*)&lrow[(c ^ sw) * 8] = v;
        }
    }
    __syncthreads();                        // the ONLY barrier

    const int wn = wave * 64;
    const int lr = lane & 15;
    const int lk = lane >> 4;
    const int col_l = lane & 15;
    const int rbase = (lane >> 4) * 4;

    size_t woff[4];
#pragma unroll
    for (int s = 0; s < 4; ++s)
        woff[s] = (size_t)(wn + s * 16 + lr) * KPAD + lk * 8;

    // ---- pass A: rows 0..63, wave tile 64m x 64n (R4's proven K-loop) ----
    {
        f32x4 acc[4][4];
#pragma unroll
        for (int i = 0; i < 4; ++i)
#pragma unroll
            for (int j = 0; j < 4; ++j) acc[i][j] = (f32x4){0.f, 0.f, 0.f, 0.f};

        bf16x8 wa[4], wb[4], afa[4];
#pragma unroll
        for (int s = 0; s < 4; ++s) wa[s] = *(const bf16x8*)&W[woff[s]];
#pragma unroll
        for (int s = 0; s < 4; ++s) wb[s] = *(const bf16x8*)&W[woff[s] + 32];
#pragma unroll
        for (int mt = 0; mt < 4; ++mt) {
            const int row = mt * 16 + lr;
            afa[mt] = *(const bf16x8*)&At[(row * 64 + (lk ^ (row & 7))) * 8];
        }

#pragma unroll
        for (int i = 0; i < 16; ++i) {
            bf16x8 wc[4], afb[4];
            if (i + 2 < 16) {
#pragma unroll
                for (int s = 0; s < 4; ++s)
                    wc[s] = *(const bf16x8*)&W[woff[s] + (size_t)(i + 2) * 32];
            }
            if (i + 1 < 16) {
#pragma unroll
                for (int mt = 0; mt < 4; ++mt) {
                    const int row = mt * 16 + lr;
                    const int chunk = (((i + 1) * 4 + lk)) ^ (row & 7);
                    afb[mt] = *(const bf16x8*)&At[(row * 64 + chunk) * 8];
                }
            }
#pragma unroll
            for (int mt = 0; mt < 4; ++mt)
#pragma unroll
                for (int nt = 0; nt < 4; ++nt)
                    acc[mt][nt] = __builtin_amdgcn_mfma_f32_16x16x32_bf16(
                        afa[mt], wa[nt], acc[mt][nt], 0, 0, 0);
            if (i + 1 < 16) {
#pragma unroll
                for (int s = 0; s < 4; ++s) wa[s] = wb[s];
#pragma unroll
                for (int mt = 0; mt < 4; ++mt) afa[mt] = afb[mt];
            }
            if (i + 2 < 16) {
#pragma unroll
                for (int s = 0; s < 4; ++s) wb[s] = wc[s];
            }
        }

#pragma unroll
        for (int mt = 0; mt < 4; ++mt) {
            const int mbase = m0 + mt * 16 + rbase;
            int mol[4];
            if (MODE == 1) {
#pragma unroll
                for (int reg = 0; reg < 4; ++reg)
                    mol[reg] = mol_ids[min(mbase + reg, M - 1)];
            }
#pragma unroll
            for (int nt = 0; nt < 4; ++nt) {
                const int n = wn + nt * 16 + col_l;
                if (MODE == 0) {
#pragma unroll
                    for (int reg = 0; reg < 4; ++reg) {
                        const int m = mbase + reg;
                        if (m >= M) continue;
                        if (n < HIDDEN)
                            gout[(size_t)m * MSTRIDE + n] =
                                f2bf(fmaxf(acc[mt][nt][reg], 0.0f));
                        else if (n < MSTRIDE)
                            gout[(size_t)m * MSTRIDE + n] = 0;  // pad cols zero
                    }
                } else {
                    if (n >= HIDDEN) continue;
                    const float bsum = bias[n];
                    float run = 0.0f;
                    int cur = mol[0];
#pragma unroll
                    for (int reg = 0; reg < 4; ++reg) {
                        const float v = (mbase + reg < M)
                            ? fmaxf(acc[mt][nt][reg] + bsum, 0.0f) : 0.0f;
                        if (mol[reg] != cur) {
                            atomicAdd(&aout[(size_t)cur * HIDDEN + n], run);
                            cur = mol[reg];
                            run = 0.0f;
                        }
                        run += v;
                    }
                    atomicAdd(&aout[(size_t)cur * HIDDEN + n], run);
                }
            }
        }
    }

    // ---- pass B: rows 64..79, wave tile 16m x 64n (W re-read from L2) ----
    {
        f32x4 acc2[4];
#pragma unroll
        for (int j = 0; j < 4; ++j) acc2[j] = (f32x4){0.f, 0.f, 0.f, 0.f};

        const int rowb = 64 + lr;
        bf16x8 wa[4], wb[4];
#pragma unroll
        for (int s = 0; s < 4; ++s) wa[s] = *(const bf16x8*)&W[woff[s]];
#pragma unroll
        for (int s = 0; s < 4; ++s) wb[s] = *(const bf16x8*)&W[woff[s] + 32];
        bf16x8 afa = *(const bf16x8*)&At[(rowb * 64 + (lk ^ (rowb & 7))) * 8];

#pragma unroll
        for (int i = 0; i < 16; ++i) {
            bf16x8 wc[4], afb;
            if (i + 2 < 16) {
#pragma unroll
                for (int s = 0; s < 4; ++s)
                    wc[s] = *(const bf16x8*)&W[woff[s] + (size_t)(i + 2) * 32];
            }
            if (i + 1 < 16) {
                const int chunk = (((i + 1) * 4 + lk)) ^ (rowb & 7);
                afb = *(const bf16x8*)&At[(rowb * 64 + chunk) * 8];
            }
#pragma unroll
            for (int nt = 0; nt < 4; ++nt)
                acc2[nt] = __builtin_amdgcn_mfma_f32_16x16x32_bf16(
                    afa, wa[nt], acc2[nt], 0, 0, 0);
            if (i + 1 < 16) {
#pragma unroll
                for (int s = 0; s < 4; ++s) wa[s] = wb[s];
                afa = afb;
            }
            if (i + 2 < 16) {
#pragma unroll
                for (int s = 0; s < 4; ++s) wb[s] = wc[s];
            }
        }

        const int mbase = m0 + 64 + rbase;
        int mol[4];
        if (MODE == 1) {
#pragma unroll
            for (int reg = 0; reg < 4; ++reg)
                mol[reg] = mol_ids[min(mbase + reg, M - 1)];
        }
#pragma unroll
        for (int nt = 0; nt < 4; ++nt) {
            const int n = wn + nt * 16 + col_l;
            if (MODE == 0) {
#pragma unroll
                for (int reg = 0; reg < 4; ++reg) {
                    const int m = mbase + reg;
                    if (m >= M) continue;
                    if (n < HIDDEN)
                        gout[(size_t)m * MSTRIDE + n] =
                            f2bf(fmaxf(acc2[nt][reg], 0.0f));
                    else if (n < MSTRIDE)
                        gout[(size_t)m * MSTRIDE + n] = 0;   // pad cols zero
                }
            } else {
                if (n >= HIDDEN) continue;
                const float bsum = bias[n];
                float run = 0.0f;
                int cur = mol[0];
#pragma unroll
                for (int reg = 0; reg < 4; ++reg) {
                    const float v = (mbase + reg < M)
                        ? fmaxf(acc2[nt][reg] + bsum, 0.0f) : 0.0f;
                    if (mol[reg] != cur) {
                        atomicAdd(&aout[(size_t)cur * HIDDEN + n], run);
                        cur = mol[reg];
                        run = 0.0f;
                    }
                    run += v;
                }
                atomicAdd(&aout[(size_t)cur * HIDDEN + n], run);
            }
        }
    }
}

// ---------------- molecule mean ----------------
__global__ __launch_bounds__(256) void count_atoms(const int* __restrict__ mol_ids,
                                                   float* __restrict__ counts) {
    const int a = blockIdx.x * 256 + threadIdx.x;
    if (a < N_ATOMS) atomicAdd(&counts[mol_ids[a]], 1.0f);
}
__global__ __launch_bounds__(256) void div_counts(float* __restrict__ out,
                                                  const float* __restrict__ counts) {
    const int i = blockIdx.x * 256 + threadIdx.x;
    if (i < N_MOLS * HIDDEN) out[i] = out[i] / counts[i / HIDDEN];
}

extern "C" void kernel_launch(void* const* d_in, const int* in_sizes, int n_in,
                              void* d_out, int out_size, void* d_ws, size_t ws_size,
                              hipStream_t stream) {
    const float* fatoms  = (const float*)d_in[0];
    const float* fbonds  = (const float*)d_in[1];
    const int*   agraph  = (const int*)d_in[2];
    const int*   bgraph  = (const int*)d_in[3];
    const int*   mol_ids = (const int*)d_in[4];
    const float* tree    = (const float*)d_in[6];
    const float* W_i     = (const float*)d_in[7];
    const float* W_h     = (const float*)d_in[8];
    const float* W_o     = (const float*)d_in[9];
    const float* b_o     = (const float*)d_in[10];
    float* out = (float*)d_out;

    ushort* zrow   = (ushort*)d_ws;                        // 512 (912B zero row, padded)
    ushort* Abuf   = zrow   + 512;                         // 40000 x 64 (feat chunks)
    ushort* Aout   = Abuf   + (size_t)N_BONDS * FSTRIDE;   // 20000 x 64
    ushort* gmsgA  = Aout   + (size_t)N_ATOMS * FSTRIDE;   // 40000 x 456
    ushort* gmsgB  = gmsgA  + (size_t)N_BONDS * MSTRIDE;   // 40000 x 456
    ushort* tbuf   = gmsgB  + (size_t)N_BONDS * MSTRIDE;   // 16000 x 456
    ushort* Wcat   = tbuf   + (size_t)N_MESS  * MSTRIDE;   // 512 x 512
    ushort* Wocat  = Wcat   + (size_t)KPAD * KPAD;         // 512 x 512
    ushort* base_b = Wocat  + (size_t)KPAD * KPAD;         // 40000 x 456
    ushort* base_a = base_b + (size_t)N_BONDS * MSTRIDE;   // 20000 x 456
    float*  counts = (float*)(base_a + (size_t)N_ATOMS * MSTRIDE);

    (void)hipMemsetAsync(d_out, 0, (size_t)N_MOLS * HIDDEN * sizeof(float), stream);
    (void)hipMemsetAsync(counts, 0, N_MOLS * sizeof(float), stream);
    (void)hipMemsetAsync(zrow, 0, 512 * sizeof(ushort), stream);

    const dim3 blk(256);
    pack_tree <<<N_MESS, blk, 0, stream>>>(tree, tbuf);
    pack_bonds<<<(N_BONDS + 3) / 4, blk, 0, stream>>>(fbonds, Abuf);
    pack_atoms<<<(N_ATOMS + 3) / 4, blk, 0, stream>>>(fatoms, Aout);
    pack_w    <<<KPAD, blk, 0, stream>>>(W_i, W_h, W_o, Wcat, Wocat);
    precompute_base<<<(N_BONDS + 3) / 4, blk, 0, stream>>>(bgraph, tbuf, base_b, N_BONDS);
    precompute_base<<<(N_ATOMS + 3) / 4, blk, 0, stream>>>(agraph, tbuf, base_a, N_ATOMS);

    const int mt64 = (N_BONDS + 63) / 64;                // 625 (first GEMM, 64-row)
    const dim3 gB0(((mt64 + 7) / 8) * 16);               // first GEMM grid (2 n-blks)

    // gmsgA = relu(fbonds @ W_i^T): nei cols zero, K=64 suffices
    mfma_gemm0<2, FSTRIDE><<<gB0, blk, 0, stream>>>(Abuf, N_BONDS, Wcat, gmsgA, mt64);

    // 5 fused gather+GEMM iterations, ping-pong gmsg buffers (race-free).
    // Single-round grids: bonds 500 blocks, atoms 250 blocks (1 tile each).
    const int gB = N_BONDS / BM;                         // 500
    const int gA = N_ATOMS / BM;                         // 250
    ushort* cur = gmsgA;
    ushort* nxt = gmsgB;
    const dim3 blk2(512);
    for (int it = 0; it < 5; ++it) {
        fused_gg<0><<<gB, blk2, 0, stream>>>(bgraph, base_b, cur, zrow, Abuf, Wcat,
                                             nullptr, nullptr, nxt, nullptr, N_BONDS);
        ushort* t = cur; cur = nxt; nxt = t;
    }
    // atom readout: fused gather + GEMM with bias/relu/molecule-sum epilogue
    fused_gg<1><<<gA, blk2, 0, stream>>>(agraph, base_a, cur, zrow, Aout, Wocat,
                                         b_o, mol_ids, nullptr, out, N_ATOMS);

    count_atoms<<<(N_ATOMS + 255) / 256, blk, 0, stream>>>(mol_ids, counts);
    div_counts <<<(N_MOLS * HIDDEN + 255) / 256, blk, 0, stream>>>(out, counts);
}

// Round 12
// 830.755 us; speedup vs baseline: 1.0654x; 1.0654x over previous
//
#include <hip/hip_runtime.h>

#define HIDDEN 450
#define MAX_NB 15
#define N_ATOMS 20000
#define N_BONDS 40000
#define N_MESS  16000
#define N_MOLS  1000
#define KPAD    512     // padded concat-K: [feat 0..39 | nei 40..489 | pad]
#define MSTRIDE 456     // message/base row stride = 912B = 57 x 16B chunks
#define FSTRIDE 64      // packed feature row stride (chunks 0..7)
#define BM      64      // fused-kernel M-tile (64KB LDS -> 2 blocks/CU)

typedef unsigned int uint;
typedef unsigned short ushort;
typedef __bf16 bf16x8 __attribute__((ext_vector_type(8)));
typedef float  f32x4  __attribute__((ext_vector_type(4)));

__device__ __forceinline__ ushort f2bf(float f) {
    uint u = __builtin_bit_cast(uint, f);
    u += 0x7fffu + ((u >> 16) & 1u);     // RNE
    return (ushort)(u >> 16);
}
__device__ __forceinline__ float bfhi(uint w) {
    return __builtin_bit_cast(float, w & 0xffff0000u);
}
__device__ __forceinline__ float bflo(uint w) {
    return __builtin_bit_cast(float, w << 16);
}

// ---------------- pack kernels (run once per launch) ----------------

__global__ __launch_bounds__(256) void pack_tree(const float* __restrict__ tree,
                                                 ushort* __restrict__ tbuf) {
    const int r = blockIdx.x, t = threadIdx.x;
    if (t < 228) {
        uint p = 0;
        if (t < 225) {
            const float2 v = *(const float2*)&tree[(size_t)r * HIDDEN + 2 * t];
            p = (uint)f2bf(v.x) | ((uint)f2bf(v.y) << 16);
        }
        ((uint*)(tbuf + (size_t)r * MSTRIDE))[t] = p;
    }
}

__global__ __launch_bounds__(256) void pack_bonds(const float* __restrict__ fbonds,
                                                  ushort* __restrict__ Abuf) {
    const int r = blockIdx.x * 4 + (threadIdx.x >> 6);
    const int t = threadIdx.x & 63;
    if (r >= N_BONDS) return;
    Abuf[(size_t)r * FSTRIDE + t] = (t < 40) ? f2bf(fbonds[(size_t)r * 40 + t])
                                             : (ushort)0;
}

__global__ __launch_bounds__(256) void pack_atoms(const float* __restrict__ fatoms,
                                                  ushort* __restrict__ Aout) {
    const int r = blockIdx.x * 4 + (threadIdx.x >> 6);
    const int t = threadIdx.x & 63;
    if (r >= N_ATOMS) return;
    Aout[(size_t)r * FSTRIDE + t] = (t < 35) ? f2bf(fatoms[(size_t)r * 35 + t])
                                             : (ushort)0;
}

__global__ __launch_bounds__(256) void pack_w(const float* __restrict__ W_i,
                                              const float* __restrict__ W_h,
                                              const float* __restrict__ W_o,
                                              ushort* __restrict__ Wcat,
                                              ushort* __restrict__ Wocat) {
    const int n = blockIdx.x;  // 0..511
    for (int c = threadIdx.x; c < KPAD; c += 256) {
        float v = 0.0f, vo = 0.0f;
        if (n < HIDDEN) {
            if (c < 40)       v = W_i[(size_t)n * 40 + c];
            else if (c < 490) v = W_h[(size_t)n * HIDDEN + (c - 40)];
            if (c < 35)       vo = W_o[(size_t)n * 485 + c];
            else if (c >= 40 && c < 490) vo = W_o[(size_t)n * 485 + 35 + (c - 40)];
        }
        Wcat [(size_t)n * KPAD + c] = f2bf(v);
        Wocat[(size_t)n * KPAD + c] = f2bf(vo);
    }
}

// ---------------- static-base precompute: base[r] = sum_{idx<N_MESS} tbuf[idx] ----
// Bonds only (atom pass gathers tree rows directly - R12).
// All 15 loads unconditional (invalid idx -> tbuf row 0 = zero padding slot);
// sched_barrier(0) after the batch keeps the batch in flight (MLP fence).
__global__ __launch_bounds__(256) void precompute_base(const int* __restrict__ g,
                                                       const ushort* __restrict__ tbuf,
                                                       ushort* __restrict__ base,
                                                       int nrows) {
    const int r_raw = blockIdx.x * 4 + (threadIdx.x >> 6);
    const int lane = threadIdx.x & 63;
    if (r_raw >= nrows) return;
    const int r = __builtin_amdgcn_readfirstlane(r_raw);   // wave-uniform -> SGPR
    const int* gr = g + (size_t)r * MAX_NB;
    const ushort* p[MAX_NB];
#pragma unroll
    for (int j = 0; j < MAX_NB; ++j) {
        const int idx = gr[j];
        p[j] = tbuf + (size_t)((idx < N_MESS) ? idx : 0) * MSTRIDE;
    }
    if (lane >= 57) return;
    const int off = lane * 8;
    uint4 w[MAX_NB];
#pragma unroll
    for (int j = 0; j < MAX_NB; ++j) w[j] = *(const uint4*)(p[j] + off);
    __builtin_amdgcn_sched_barrier(0);     // MLP fence: no sums above this line
    float acc[8] = {};
#pragma unroll
    for (int j = 0; j < MAX_NB; ++j) {
        acc[0] += bflo(w[j].x); acc[1] += bfhi(w[j].x);
        acc[2] += bflo(w[j].y); acc[3] += bfhi(w[j].y);
        acc[4] += bflo(w[j].z); acc[5] += bfhi(w[j].z);
        acc[6] += bflo(w[j].w); acc[7] += bfhi(w[j].w);
    }
    uint4 o;
    o.x = (uint)f2bf(acc[0]) | ((uint)f2bf(acc[1]) << 16);
    o.y = (uint)f2bf(acc[2]) | ((uint)f2bf(acc[3]) << 16);
    o.z = (uint)f2bf(acc[4]) | ((uint)f2bf(acc[5]) << 16);
    o.w = (uint)f2bf(acc[6]) | ((uint)f2bf(acc[7]) << 16);
    *(uint4*)(base + (size_t)r * MSTRIDE + off) = o;
}

// ---------------- first GEMM (K=64 on raw bond feats) ----------------
// C[M x 450] = relu(A[M x K] . W[450 x K]^T), K = KT*32, A stride AST ushorts.
template <int KT, int AST>
__global__ __launch_bounds__(256, 2) void mfma_gemm0(
    const ushort* __restrict__ A, int M,
    const ushort* __restrict__ W,
    ushort* __restrict__ gout, int mtiles) {
    __shared__ ushort At[64 * KT * 32];
    const int tid = threadIdx.x;
    const int id  = blockIdx.x;
    const int b     = id & 7;               // XCD residue
    const int n_blk = (id >> 3) & 1;
    const int m_blk = (id >> 4) * 8 + b;
    if (m_blk >= mtiles) return;            // uniform early-out (before barrier)
    const int m0 = m_blk * 64, n0 = n_blk * 256;
    const int CPR = KT * 4;                 // 16B chunks per LDS row

    {
        const int srow = tid >> 2;
        const int c0   = tid & 3;
        const ushort* gsrc = A + (size_t)min(m0 + srow, M - 1) * AST;
        ushort* lrow = At + srow * (KT * 32);
#pragma unroll
        for (int c = c0; c < CPR; c += 4) {
            const uint4 v = *(const uint4*)(gsrc + c * 8);
            *(uint4*)&lrow[(c ^ (srow & 7)) * 8] = v;
        }
    }
    __syncthreads();

    const int lane = tid & 63;
    const int wave = tid >> 6;
    const int wn = wave * 64;
    const int lr = lane & 15;
    const int lk = lane >> 4;

    size_t woff[4];
#pragma unroll
    for (int s = 0; s < 4; ++s)
        woff[s] = (size_t)(n0 + wn + s * 16 + lr) * KPAD + lk * 8;

    f32x4 acc[4][4];
#pragma unroll
    for (int i = 0; i < 4; ++i)
#pragma unroll
        for (int j = 0; j < 4; ++j) acc[i][j] = (f32x4){0.f, 0.f, 0.f, 0.f};

    bf16x8 wa[4], wb[4], afa[4];
#pragma unroll
    for (int s = 0; s < 4; ++s) wa[s] = *(const bf16x8*)&W[woff[s]];
#pragma unroll
    for (int s = 0; s < 4; ++s)
        wb[s] = (KT > 1) ? *(const bf16x8*)&W[woff[s] + 32] : wa[s];
#pragma unroll
    for (int mt = 0; mt < 4; ++mt) {
        const int row = mt * 16 + lr;
        afa[mt] = *(const bf16x8*)&At[(row * CPR + (lk ^ (row & 7))) * 8];
    }

#pragma unroll
    for (int i = 0; i < KT; ++i) {
        bf16x8 wc[4], afb[4];
        if (i + 2 < KT) {
#pragma unroll
            for (int s = 0; s < 4; ++s)
                wc[s] = *(const bf16x8*)&W[woff[s] + (size_t)(i + 2) * 32];
        }
        if (i + 1 < KT) {
#pragma unroll
            for (int mt = 0; mt < 4; ++mt) {
                const int row = mt * 16 + lr;
                const int chunk = (((i + 1) * 4 + lk)) ^ (row & 7);
                afb[mt] = *(const bf16x8*)&At[(row * CPR + chunk) * 8];
            }
        }
#pragma unroll
        for (int mt = 0; mt < 4; ++mt)
#pragma unroll
            for (int nt = 0; nt < 4; ++nt)
                acc[mt][nt] = __builtin_amdgcn_mfma_f32_16x16x32_bf16(
                    afa[mt], wa[nt], acc[mt][nt], 0, 0, 0);
        if (i + 1 < KT) {
#pragma unroll
            for (int s = 0; s < 4; ++s) wa[s] = wb[s];
#pragma unroll
            for (int mt = 0; mt < 4; ++mt) afa[mt] = afb[mt];
        }
        if (i + 2 < KT) {
#pragma unroll
            for (int s = 0; s < 4; ++s) wb[s] = wc[s];
        }
    }

    const int col_l = lane & 15;
    const int rbase = (lane >> 4) * 4;
#pragma unroll
    for (int mt = 0; mt < 4; ++mt) {
        const int mbase = m0 + mt * 16 + rbase;
#pragma unroll
        for (int nt = 0; nt < 4; ++nt) {
            const int n = n0 + wn + nt * 16 + col_l;
#pragma unroll
            for (int reg = 0; reg < 4; ++reg) {
                const int m = mbase + reg;
                if (m >= M) continue;
                if (n < HIDDEN)
                    gout[(size_t)m * MSTRIDE + n] = f2bf(fmaxf(acc[mt][nt][reg], 0.0f));
                else if (n < MSTRIDE)
                    gout[(size_t)m * MSTRIDE + n] = 0;   // keep pad cols zero
            }
        }
    }
}

// ---------------- fused gather + GEMM ----------------
// Per block: BM=64 rows x full N=512. 8 waves / 512 threads; LDS 64KB ->
// 2 blocks/CU (16 waves). PROVEN SHAPE (R4/R10: 119us/dispatch, FETCH 221 /
// WRITE 36 MB): static 625-block grid, 1 tile per block. All rebalancing
// variants (persistent queue R5/R6, BM16 R8, mixed 1-2 tile R9, BM80
// single-round R11) either amplified HBM traffic or left the rate at 2.2
// TB/s - the rate is pinned by the unified register file: 16 waves/CU x
// ~64 data-VGPRs of in-flight gather per lane. Do not deviate.
// Stage: each wave gather-sums 8 rows straight into the swizzled LDS A-tile.
// MLP fence: all loads issue back-to-back, then sched_barrier(0), then sums.
// MODE 0 (bonds): tree neighbors pre-summed in base; invalid -> 912B zero
// row. MODE 1 (atoms): NO base - gathers tree rows directly from tmsg
// (reference semantics message=[tree;graph]; tbuf row 0 is the zero pad
// slot), verified correct in R8/R9; kills the atom precompute dispatch.
// K-loop: wave tile 64m x 64n, KT=16, W prefetch 2 deep, A-frag 1 deep.
// MODE 0: bf16 store to gout. MODE 1: bias+relu+molecule atomicAdd (run-merge).
template <int MODE>
__global__ __launch_bounds__(512, 4) void fused_gg(
    const int* __restrict__ g,
    const ushort* __restrict__ base,   // MODE 0 only
    const ushort* __restrict__ gin,
    const ushort* __restrict__ zrow,   // MODE 0 only
    const ushort* __restrict__ tmsg,   // MODE 1 only (= tbuf)
    const ushort* __restrict__ feat,
    const ushort* __restrict__ W,
    const float* __restrict__ bias, const int* __restrict__ mol_ids,
    ushort* __restrict__ gout, float* __restrict__ aout, int M) {
    __shared__ ushort At[BM * KPAD];        // 64 rows x 64 chunks, 64KB
    const int tid  = threadIdx.x;
    const int lane = tid & 63;
    const int wave = tid >> 6;
    const int m0 = blockIdx.x * BM;

    // ---- stage: gather-sum directly into swizzled LDS (8 rows per wave) ----
#pragma unroll 1
    for (int rr = 0; rr < 8; ++rr) {
        const int r = (wave << 3) | rr;
        const int m = __builtin_amdgcn_readfirstlane(min(m0 + r, M - 1));
        const int sw = r & 7;
        ushort* lrow = At + r * KPAD;
        const int* gr = g + (size_t)m * MAX_NB;
        const ushort* p[MAX_NB];
#pragma unroll
        for (int j = 0; j < MAX_NB; ++j) {
            const int idx = gr[j];
            const int row = idx - N_MESS;
            if (MODE == 0)
                p[j] = (row >= 0) ? gin + (size_t)row * MSTRIDE : zrow;
            else
                p[j] = (row >= 0) ? gin + (size_t)row * MSTRIDE
                                  : tmsg + (size_t)idx * MSTRIDE;
        }
        if (lane < 57) {
            const int off = lane * 8;
            float acc[8];
            uint4 w[MAX_NB];
            if (MODE == 0) {
                const uint4 b = *(const uint4*)(base + (size_t)m * MSTRIDE + off);
#pragma unroll
                for (int j = 0; j < MAX_NB; ++j) w[j] = *(const uint4*)(p[j] + off);
                __builtin_amdgcn_sched_barrier(0);  // MLP fence: 16 loads in flight
                acc[0] = bflo(b.x); acc[1] = bfhi(b.x);
                acc[2] = bflo(b.y); acc[3] = bfhi(b.y);
                acc[4] = bflo(b.z); acc[5] = bfhi(b.z);
                acc[6] = bflo(b.w); acc[7] = bfhi(b.w);
            } else {
#pragma unroll
                for (int j = 0; j < MAX_NB; ++j) w[j] = *(const uint4*)(p[j] + off);
                __builtin_amdgcn_sched_barrier(0);  // MLP fence: 15 loads in flight
#pragma unroll
                for (int k = 0; k < 8; ++k) acc[k] = 0.0f;
            }
#pragma unroll
            for (int j = 0; j < MAX_NB; ++j) {
                acc[0] += bflo(w[j].x); acc[1] += bfhi(w[j].x);
                acc[2] += bflo(w[j].y); acc[3] += bfhi(w[j].y);
                acc[4] += bflo(w[j].z); acc[5] += bfhi(w[j].z);
                acc[6] += bflo(w[j].w); acc[7] += bfhi(w[j].w);
            }
            uint4 o;
            o.x = (uint)f2bf(acc[0]) | ((uint)f2bf(acc[1]) << 16);
            o.y = (uint)f2bf(acc[2]) | ((uint)f2bf(acc[3]) << 16);
            o.z = (uint)f2bf(acc[4]) | ((uint)f2bf(acc[5]) << 16);
            o.w = (uint)f2bf(acc[6]) | ((uint)f2bf(acc[7]) << 16);
            *(uint4*)&lrow[((5 + lane) ^ sw) * 8] = o;   // nei chunks 5..61
        } else {
            const int c = (lane < 62) ? (lane - 57) : lane;  // feat 0..4 | pad 62,63
            uint4 v = (uint4){0u, 0u, 0u, 0u};
            if (lane < 62)
                v = *(const uint4*)(feat + (size_t)m * FSTRIDE + (lane - 57) * 8);
            *(uint4*)&lrow[(c ^ sw) * 8] = v;
        }
    }
    __syncthreads();                        // the ONLY barrier

    // ---- K-loop: wave tile 64m x 64n, KT=16, W prefetch 2 deep, A 1 deep ----
    const int wn = wave * 64;
    const int lr = lane & 15;
    const int lk = lane >> 4;

    size_t woff[4];
#pragma unroll
    for (int s = 0; s < 4; ++s)
        woff[s] = (size_t)(wn + s * 16 + lr) * KPAD + lk * 8;

    f32x4 acc[4][4];
#pragma unroll
    for (int i = 0; i < 4; ++i)
#pragma unroll
        for (int j = 0; j < 4; ++j) acc[i][j] = (f32x4){0.f, 0.f, 0.f, 0.f};

    bf16x8 wa[4], wb[4], afa[4];
#pragma unroll
    for (int s = 0; s < 4; ++s) wa[s] = *(const bf16x8*)&W[woff[s]];
#pragma unroll
    for (int s = 0; s < 4; ++s) wb[s] = *(const bf16x8*)&W[woff[s] + 32];
#pragma unroll
    for (int mt = 0; mt < 4; ++mt) {
        const int row = mt * 16 + lr;
        afa[mt] = *(const bf16x8*)&At[(row * 64 + (lk ^ (row & 7))) * 8];
    }

#pragma unroll
    for (int i = 0; i < 16; ++i) {
        bf16x8 wc[4], afb[4];
        if (i + 2 < 16) {
#pragma unroll
            for (int s = 0; s < 4; ++s)
                wc[s] = *(const bf16x8*)&W[woff[s] + (size_t)(i + 2) * 32];
        }
        if (i + 1 < 16) {
#pragma unroll
            for (int mt = 0; mt < 4; ++mt) {
                const int row = mt * 16 + lr;
                const int chunk = (((i + 1) * 4 + lk)) ^ (row & 7);
                afb[mt] = *(const bf16x8*)&At[(row * 64 + chunk) * 8];
            }
        }
#pragma unroll
        for (int mt = 0; mt < 4; ++mt)
#pragma unroll
            for (int nt = 0; nt < 4; ++nt)
                acc[mt][nt] = __builtin_amdgcn_mfma_f32_16x16x32_bf16(
                    afa[mt], wa[nt], acc[mt][nt], 0, 0, 0);
        if (i + 1 < 16) {
#pragma unroll
            for (int s = 0; s < 4; ++s) wa[s] = wb[s];
#pragma unroll
            for (int mt = 0; mt < 4; ++mt) afa[mt] = afb[mt];
        }
        if (i + 2 < 16) {
#pragma unroll
            for (int s = 0; s < 4; ++s) wb[s] = wc[s];
        }
    }

    const int col_l = lane & 15;
    const int rbase = (lane >> 4) * 4;
#pragma unroll
    for (int mt = 0; mt < 4; ++mt) {
        const int mbase = m0 + mt * 16 + rbase;
        int mol[4];
        if (MODE == 1) {
#pragma unroll
            for (int reg = 0; reg < 4; ++reg)
                mol[reg] = mol_ids[min(mbase + reg, M - 1)];
        }
#pragma unroll
        for (int nt = 0; nt < 4; ++nt) {
            const int n = wn + nt * 16 + col_l;
            if (MODE == 0) {
#pragma unroll
                for (int reg = 0; reg < 4; ++reg) {
                    const int m = mbase + reg;
                    if (m >= M) continue;
                    if (n < HIDDEN)
                        gout[(size_t)m * MSTRIDE + n] = f2bf(fmaxf(acc[mt][nt][reg], 0.0f));
                    else if (n < MSTRIDE)
                        gout[(size_t)m * MSTRIDE + n] = 0;   // keep pad cols zero
                }
            } else {
                if (n >= HIDDEN) continue;
                const float bsum = bias[n];
                float run = 0.0f;
                int cur = mol[0];
#pragma unroll
                for (int reg = 0; reg < 4; ++reg) {
                    const float v = (mbase + reg < M)
                        ? fmaxf(acc[mt][nt][reg] + bsum, 0.0f) : 0.0f;
                    if (mol[reg] != cur) {
                        atomicAdd(&aout[(size_t)cur * HIDDEN + n], run);
                        cur = mol[reg];
                        run = 0.0f;
                    }
                    run += v;
                }
                atomicAdd(&aout[(size_t)cur * HIDDEN + n], run);
            }
        }
    }
}

// ---------------- molecule mean ----------------
__global__ __launch_bounds__(256) void count_atoms(const int* __restrict__ mol_ids,
                                                   float* __restrict__ counts) {
    const int a = blockIdx.x * 256 + threadIdx.x;
    if (a < N_ATOMS) atomicAdd(&counts[mol_ids[a]], 1.0f);
}
__global__ __launch_bounds__(256) void div_counts(float* __restrict__ out,
                                                  const float* __restrict__ counts) {
    const int i = blockIdx.x * 256 + threadIdx.x;
    if (i < N_MOLS * HIDDEN) out[i] = out[i] / counts[i / HIDDEN];
}

extern "C" void kernel_launch(void* const* d_in, const int* in_sizes, int n_in,
                              void* d_out, int out_size, void* d_ws, size_t ws_size,
                              hipStream_t stream) {
    const float* fatoms  = (const float*)d_in[0];
    const float* fbonds  = (const float*)d_in[1];
    const int*   agraph  = (const int*)d_in[2];
    const int*   bgraph  = (const int*)d_in[3];
    const int*   mol_ids = (const int*)d_in[4];
    const float* tree    = (const float*)d_in[6];
    const float* W_i     = (const float*)d_in[7];
    const float* W_h     = (const float*)d_in[8];
    const float* W_o     = (const float*)d_in[9];
    const float* b_o     = (const float*)d_in[10];
    float* out = (float*)d_out;

    ushort* zrow   = (ushort*)d_ws;                        // 512 (912B zero row, padded)
    ushort* Abuf   = zrow   + 512;                         // 40000 x 64 (feat chunks)
    ushort* Aout   = Abuf   + (size_t)N_BONDS * FSTRIDE;   // 20000 x 64
    ushort* gmsgA  = Aout   + (size_t)N_ATOMS * FSTRIDE;   // 40000 x 456
    ushort* gmsgB  = gmsgA  + (size_t)N_BONDS * MSTRIDE;   // 40000 x 456
    ushort* tbuf   = gmsgB  + (size_t)N_BONDS * MSTRIDE;   // 16000 x 456
    ushort* Wcat   = tbuf   + (size_t)N_MESS  * MSTRIDE;   // 512 x 512
    ushort* Wocat  = Wcat   + (size_t)KPAD * KPAD;         // 512 x 512
    ushort* base_b = Wocat  + (size_t)KPAD * KPAD;         // 40000 x 456
    float*  counts = (float*)(base_b + (size_t)N_BONDS * MSTRIDE);

    (void)hipMemsetAsync(d_out, 0, (size_t)N_MOLS * HIDDEN * sizeof(float), stream);
    (void)hipMemsetAsync(counts, 0, N_MOLS * sizeof(float), stream);
    (void)hipMemsetAsync(zrow, 0, 512 * sizeof(ushort), stream);

    const dim3 blk(256);
    pack_tree <<<N_MESS, blk, 0, stream>>>(tree, tbuf);
    pack_bonds<<<(N_BONDS + 3) / 4, blk, 0, stream>>>(fbonds, Abuf);
    pack_atoms<<<(N_ATOMS + 3) / 4, blk, 0, stream>>>(fatoms, Aout);
    pack_w    <<<KPAD, blk, 0, stream>>>(W_i, W_h, W_o, Wcat, Wocat);
    // bonds only - atom pass gathers tree rows directly (R12)
    precompute_base<<<(N_BONDS + 3) / 4, blk, 0, stream>>>(bgraph, tbuf, base_b, N_BONDS);

    const int mtB = (N_BONDS + 63) / 64;                 // 625
    const int mtA = (N_ATOMS + 63) / 64;                 // 313
    const dim3 gB0(((mtB + 7) / 8) * 16);                // first GEMM grid (2 n-blks)

    // gmsgA = relu(fbonds @ W_i^T): nei cols zero, K=64 suffices
    mfma_gemm0<2, FSTRIDE><<<gB0, blk, 0, stream>>>(Abuf, N_BONDS, Wcat, gmsgA, mtB);

    // 5 fused gather+GEMM iterations, ping-pong gmsg buffers (race-free)
    ushort* cur = gmsgA;
    ushort* nxt = gmsgB;
    const dim3 blk2(512);
    for (int it = 0; it < 5; ++it) {
        fused_gg<0><<<mtB, blk2, 0, stream>>>(bgraph, base_b, cur, zrow, tbuf,
                                              Abuf, Wcat, nullptr, nullptr,
                                              nxt, nullptr, N_BONDS);
        ushort* t = cur; cur = nxt; nxt = t;
    }
    // atom readout: gathers tree rows directly (no precomputed base), bias+
    // relu+molecule-sum epilogue
    fused_gg<1><<<mtA, blk2, 0, stream>>>(agraph, nullptr, cur, nullptr, tbuf,
                                          Aout, Wocat, b_o, mol_ids,
                                          nullptr, out, N_ATOMS);

    count_atoms<<<(N_ATOMS + 255) / 256, blk, 0, stream>>>(mol_ids, counts);
    div_counts <<<(N_MOLS * HIDDEN + 255) / 256, blk, 0, stream>>>(out, counts);
}